// Round 2
// baseline (3165.740 us; speedup 1.0000x reference)
//
#include <hip/hip_runtime.h>
#include <hip/hip_bf16.h>
#include <stdint.h>

typedef __hip_bfloat16 bf16;
typedef __bf16 bf16x8 __attribute__((ext_vector_type(8)));
typedef float f32x4 __attribute__((ext_vector_type(4)));

#define NEDGE 500000
#define NUN   50000
#define NVN   50000

__device__ __forceinline__ float b2f(bf16 v) { return __bfloat162float(v); }

// float atomic max via sign-split int/uint atomics; m initialized to -inf.
__device__ __forceinline__ void atomicMaxF(float* addr, float val) {
    int iv = __float_as_int(val);
    if (iv >= 0) atomicMax((int*)addr, iv);
    else         atomicMin((unsigned int*)addr, (unsigned int)iv);
}

// ---------------------------------------------------------------------------
// Node GEMM: C[N,dout] = A[N,din] @ W[din,dout] + bias.
// A: f32 (A_BF16=false) or bf16 (A_BF16=true). W/bias: f32 (converted to bf16
// fragments on the fly). Out: f32 or bf16 per OUT_BF16.
// Block = 256 (4 waves); block tile = 64 rows; wave tile = 16 rows.
// MFMA 16x16x32 bf16. A frag: A[m=lane&15][k=quad*8+j]. C/D: col=lane&15,
// row=quad*4+reg (m89-verified).
// ---------------------------------------------------------------------------
template<bool A_BF16, bool OUT_BF16>
__global__ __launch_bounds__(256) void gemm_node(
    const void* __restrict__ A_, const float* __restrict__ W,
    const float* __restrict__ bias, int N, int din, int dout,
    void* __restrict__ out_, int ostride, int ocol)
{
    __shared__ __align__(16) bf16 wt[26112]; // max dout*(din+8) = 192*136
    const int tid = threadIdx.x;
    const int stride = din + 8; // rows stay 16B-aligned (din mult of 8)
    for (int k = 0; k < din; ++k) {
        if (tid < dout) wt[tid * stride + k] = __float2bfloat16(W[k * dout + tid]);
    }
    __syncthreads();

    const int wave = tid >> 6, lane = tid & 63;
    const int m16 = lane & 15, quad = lane >> 4;
    const int row0 = blockIdx.x * 64 + wave * 16;
    int arow = row0 + m16; if (arow >= N) arow = N - 1;

    const bf16*  aptrb = A_BF16 ? ((const bf16*)A_) + (size_t)arow * din + quad * 8 : nullptr;
    const float* aptrf = A_BF16 ? nullptr : ((const float*)A_) + (size_t)arow * din + quad * 8;

    const int nct = dout >> 4;
    for (int ct = 0; ct < nct; ++ct) {
        f32x4 acc = {0.f, 0.f, 0.f, 0.f};
        const bf16* bbase = &wt[(ct * 16 + m16) * stride + quad * 8];
        for (int k0 = 0; k0 < din; k0 += 32) {
            bf16x8 af;
            if (A_BF16) {
                af = *(const bf16x8*)(aptrb + k0);
            } else {
                float4 f0 = *(const float4*)(aptrf + k0);
                float4 f1 = *(const float4*)(aptrf + k0 + 4);
                af[0] = (__bf16)f0.x; af[1] = (__bf16)f0.y;
                af[2] = (__bf16)f0.z; af[3] = (__bf16)f0.w;
                af[4] = (__bf16)f1.x; af[5] = (__bf16)f1.y;
                af[6] = (__bf16)f1.z; af[7] = (__bf16)f1.w;
            }
            bf16x8 bfr = *(const bf16x8*)(bbase + k0);
            acc = __builtin_amdgcn_mfma_f32_16x16x32_bf16(af, bfr, acc, 0, 0, 0);
        }
        const int c = ct * 16 + m16;
        const float bv = bias[c];
        #pragma unroll
        for (int r = 0; r < 4; ++r) {
            int row = row0 + quad * 4 + r;
            if (row < N) {
                size_t idx = (size_t)row * ostride + ocol + c;
                float val = acc[r] + bv;
                if (OUT_BF16) ((bf16*)out_)[idx] = __float2bfloat16(val);
                else          ((float*)out_)[idx] = val;
            }
        }
    }
}

// ---------------------------------------------------------------------------
// Edge GEMM fused with gather-add epilogue (f32 in, f32 out):
// he[e,:] = e_feat[e,:]@e_lin_w + e_lin_b + he_u[u_idx[e],:] + he_v[v_idx[e],:]
// he_u/he_v are bf16 workspace buffers.
// ---------------------------------------------------------------------------
__global__ __launch_bounds__(256) void gemm_edge(
    const float* __restrict__ A, const float* __restrict__ W,
    const float* __restrict__ bias,
    const int* __restrict__ u_idx, const int* __restrict__ v_idx,
    const bf16* __restrict__ he_u, const bf16* __restrict__ he_v,
    float* __restrict__ out)
{
    __shared__ __align__(16) bf16 wt[128 * 72];
    const int din = 64, dout = 128, stride = 72;
    const int tid = threadIdx.x;
    for (int k = 0; k < din; ++k) {
        if (tid < dout) wt[tid * stride + k] = __float2bfloat16(W[k * dout + tid]);
    }
    __syncthreads();

    const int wave = tid >> 6, lane = tid & 63;
    const int m16 = lane & 15, quad = lane >> 4;
    const int row0 = blockIdx.x * 64 + wave * 16;
    int arow = row0 + m16; if (arow >= NEDGE) arow = NEDGE - 1;
    const float* aptr = A + (size_t)arow * din + quad * 8;

    bf16x8 af;
    {
        float4 f0 = *(const float4*)(aptr);
        float4 f1 = *(const float4*)(aptr + 4);
        af[0] = (__bf16)f0.x; af[1] = (__bf16)f0.y;
        af[2] = (__bf16)f0.z; af[3] = (__bf16)f0.w;
        af[4] = (__bf16)f1.x; af[5] = (__bf16)f1.y;
        af[6] = (__bf16)f1.z; af[7] = (__bf16)f1.w;
    }
    bf16x8 af2;
    {
        float4 f0 = *(const float4*)(aptr + 32);
        float4 f1 = *(const float4*)(aptr + 36);
        af2[0] = (__bf16)f0.x; af2[1] = (__bf16)f0.y;
        af2[2] = (__bf16)f0.z; af2[3] = (__bf16)f0.w;
        af2[4] = (__bf16)f1.x; af2[5] = (__bf16)f1.y;
        af2[6] = (__bf16)f1.z; af2[7] = (__bf16)f1.w;
    }

    int us[4], vs[4];
    #pragma unroll
    for (int r = 0; r < 4; ++r) {
        int row = row0 + quad * 4 + r;
        int rc = row < NEDGE ? row : NEDGE - 1;
        us[r] = u_idx[rc];
        vs[r] = v_idx[rc];
    }

    for (int ct = 0; ct < 8; ++ct) {
        f32x4 acc = {0.f, 0.f, 0.f, 0.f};
        const bf16* bbase = &wt[(ct * 16 + m16) * stride + quad * 8];
        bf16x8 b0 = *(const bf16x8*)(bbase);
        bf16x8 b1 = *(const bf16x8*)(bbase + 32);
        acc = __builtin_amdgcn_mfma_f32_16x16x32_bf16(af,  b0, acc, 0, 0, 0);
        acc = __builtin_amdgcn_mfma_f32_16x16x32_bf16(af2, b1, acc, 0, 0, 0);
        const int c = ct * 16 + m16;
        const float bv = bias[c];
        #pragma unroll
        for (int r = 0; r < 4; ++r) {
            int row = row0 + quad * 4 + r;
            if (row < NEDGE) {
                float val = acc[r] + bv
                          + b2f(he_u[(size_t)us[r] * 128 + c])
                          + b2f(he_v[(size_t)vs[r] * 128 + c]);
                out[(size_t)row * 128 + c] = val;
            }
        }
    }
}

// ---------------------------------------------------------------------------
// Attention edge passes. One wave per edge; lane j covers features j, j+64,
// j+128.  h[f] = (f<128 ? he_src[src][f] : e_feat[e][f-128]);
// x[f] = h[f] * h_att[dst][f].  Pass 1: atomic max.  Pass 2: atomic sum of
// exp and of h*exp.  e_feat f32; he_src/h_att bf16 ws; m/s/t f32 ws.
// ---------------------------------------------------------------------------
__global__ __launch_bounds__(256) void attn_max(
    const float* __restrict__ e_feat, const int* __restrict__ dst_idx,
    const int* __restrict__ src_idx, const bf16* __restrict__ he_src,
    const bf16* __restrict__ h_att, float* __restrict__ m)
{
    int tid = blockIdx.x * 256 + threadIdx.x;
    int e = tid >> 6, j = tid & 63;
    int d = dst_idx[e], s = src_idx[e];
    const bf16* hs = he_src + (size_t)s * 128;
    const bf16* ha = h_att + (size_t)d * 192;
    float hv0 = b2f(hs[j]);
    float hv1 = b2f(hs[j + 64]);
    float hv2 = e_feat[(size_t)e * 64 + j];
    float x0 = hv0 * b2f(ha[j]);
    float x1 = hv1 * b2f(ha[j + 64]);
    float x2 = hv2 * b2f(ha[j + 128]);
    float* mr = m + (size_t)d * 192;
    atomicMaxF(mr + j, x0);
    atomicMaxF(mr + j + 64, x1);
    atomicMaxF(mr + j + 128, x2);
}

__global__ __launch_bounds__(256) void attn_sum(
    const float* __restrict__ e_feat, const int* __restrict__ dst_idx,
    const int* __restrict__ src_idx, const bf16* __restrict__ he_src,
    const bf16* __restrict__ h_att, const float* __restrict__ m,
    float* __restrict__ s_arr, float* __restrict__ t_arr)
{
    int tid = blockIdx.x * 256 + threadIdx.x;
    int e = tid >> 6, j = tid & 63;
    int d = dst_idx[e], s = src_idx[e];
    const bf16* hs = he_src + (size_t)s * 128;
    const bf16* ha = h_att + (size_t)d * 192;
    float hv0 = b2f(hs[j]);
    float hv1 = b2f(hs[j + 64]);
    float hv2 = e_feat[(size_t)e * 64 + j];
    float x0 = hv0 * b2f(ha[j]);
    float x1 = hv1 * b2f(ha[j + 64]);
    float x2 = hv2 * b2f(ha[j + 128]);
    const float* mr = m + (size_t)d * 192;
    float* sr = s_arr + (size_t)d * 192;
    float* tr = t_arr + (size_t)d * 192;
    float e0 = __expf(x0 - mr[j]);
    float e1 = __expf(x1 - mr[j + 64]);
    float e2 = __expf(x2 - mr[j + 128]);
    atomicAdd(sr + j,        e0); atomicAdd(tr + j,        hv0 * e0);
    atomicAdd(sr + j + 64,   e1); atomicAdd(tr + j + 64,   hv1 * e1);
    atomicAdd(sr + j + 128,  e2); atomicAdd(tr + j + 128,  hv2 * e2);
}

__global__ __launch_bounds__(256) void init_mst(
    float* __restrict__ m, float* __restrict__ s, float* __restrict__ t)
{
    int i = blockIdx.x * 256 + threadIdx.x;
    m[i] = __uint_as_float(0xFF800000u); // -inf
    s[i] = 0.f;
    t[i] = 0.f;
}

__global__ __launch_bounds__(256) void make_agg(
    const float* __restrict__ s, const float* __restrict__ t,
    bf16* __restrict__ agg)
{
    int i = blockIdx.x * 256 + threadIdx.x;
    float sv = s[i];
    agg[i] = __float2bfloat16(sv > 0.f ? t[i] / sv : 0.f);
}

// ---------------------------------------------------------------------------

extern "C" void kernel_launch(void* const* d_in, const int* in_sizes, int n_in,
                              void* d_out, int out_size, void* d_ws, size_t ws_size,
                              hipStream_t stream)
{
    const float* e_feat   = (const float*)d_in[0];
    const float* u_feat   = (const float*)d_in[1];
    const float* v_feat   = (const float*)d_in[2];
    const int*   u_idx    = (const int*)d_in[3];
    const int*   v_idx    = (const int*)d_in[4];
    const float* e_lin_w  = (const float*)d_in[5];
    const float* e_lin_b  = (const float*)d_in[6];
    const float* u_lin_w  = (const float*)d_in[7];
    const float* u_lin_b  = (const float*)d_in[8];
    const float* v_lin_w  = (const float*)d_in[9];
    const float* v_lin_b  = (const float*)d_in[10];
    const float* attn_u_w = (const float*)d_in[11];
    const float* attn_u_b = (const float*)d_in[12];
    const float* attn_v_w = (const float*)d_in[13];
    const float* attn_v_b = (const float*)d_in[14];
    const float* W_u_w    = (const float*)d_in[15];
    const float* W_u_b    = (const float*)d_in[16];
    const float* W_v_w    = (const float*)d_in[17];
    const float* W_v_b    = (const float*)d_in[18];
    const float* Vu_w     = (const float*)d_in[19];
    const float* Vu_b     = (const float*)d_in[20];
    const float* Vv_w     = (const float*)d_in[21];
    const float* Vv_b     = (const float*)d_in[22];

    float* out = (float*)d_out;
    float* hu_out = out + (size_t)NEDGE * 128;
    float* hv_out = hu_out + (size_t)NUN * 128;

    // workspace carve-out (~198 MB)
    char* ws = (char*)d_ws;
    size_t off = 0;
    auto alloc = [&](size_t bytes) -> char* {
        char* p = ws + off;
        off += (bytes + 255) & ~(size_t)255;
        return p;
    };
    bf16*  he_u_b = (bf16*)alloc((size_t)NUN * 128 * 2);
    bf16*  he_v_b = (bf16*)alloc((size_t)NVN * 128 * 2);
    bf16*  hau_b  = (bf16*)alloc((size_t)NUN * 192 * 2);
    bf16*  hav_b  = (bf16*)alloc((size_t)NVN * 192 * 2);
    float* m_buf  = (float*)alloc((size_t)NUN * 192 * 4);
    float* s_buf  = (float*)alloc((size_t)NUN * 192 * 4);
    float* t_buf  = (float*)alloc((size_t)NUN * 192 * 4);
    bf16*  agg_b  = (bf16*)alloc((size_t)NUN * 192 * 2);

    dim3 blk(256);
    const int gnode = (NUN + 63) / 64;        // 782
    const int gedge_gemm = (NEDGE + 63) / 64; // 7813
    const int ginit = (NUN * 192) / 256;      // 37500
    const int gedge = (NEDGE * 64) / 256;     // 125000

    // node linears
    gemm_node<false, true><<<gnode, blk, 0, stream>>>(u_feat, u_lin_w, u_lin_b, NUN, 128, 128, he_u_b, 128, 0);
    gemm_node<false, true><<<gnode, blk, 0, stream>>>(v_feat, v_lin_w, v_lin_b, NVN, 128, 128, he_v_b, 128, 0);
    gemm_node<false, true><<<gnode, blk, 0, stream>>>(u_feat, attn_u_w, attn_u_b, NUN, 128, 192, hau_b, 192, 0);
    gemm_node<false, true><<<gnode, blk, 0, stream>>>(v_feat, attn_v_w, attn_v_b, NVN, 128, 192, hav_b, 192, 0);
    gemm_node<false, false><<<gnode, blk, 0, stream>>>(u_feat, Vu_w, Vu_b, NUN, 128, 64, hu_out, 128, 0);
    gemm_node<false, false><<<gnode, blk, 0, stream>>>(v_feat, Vv_w, Vv_b, NVN, 128, 64, hv_out, 128, 0);

    // he output (edge GEMM + endpoint gather-add)
    gemm_edge<<<gedge_gemm, blk, 0, stream>>>(e_feat, e_lin_w, e_lin_b, u_idx, v_idx,
                                              he_u_b, he_v_b, out);

    // u-side (backward: v -> u, dst = u_idx)
    init_mst<<<ginit, blk, 0, stream>>>(m_buf, s_buf, t_buf);
    attn_max<<<gedge, blk, 0, stream>>>(e_feat, u_idx, v_idx, he_v_b, hau_b, m_buf);
    attn_sum<<<gedge, blk, 0, stream>>>(e_feat, u_idx, v_idx, he_v_b, hau_b, m_buf, s_buf, t_buf);
    make_agg<<<ginit, blk, 0, stream>>>(s_buf, t_buf, agg_b);
    gemm_node<true, false><<<gnode, blk, 0, stream>>>(agg_b, W_u_w, W_u_b, NUN, 192, 64, hu_out, 128, 64);

    // v-side (forward: u -> v, dst = v_idx), reusing m/s/t buffers
    init_mst<<<ginit, blk, 0, stream>>>(m_buf, s_buf, t_buf);
    attn_max<<<gedge, blk, 0, stream>>>(e_feat, v_idx, u_idx, he_u_b, hav_b, m_buf);
    attn_sum<<<gedge, blk, 0, stream>>>(e_feat, v_idx, u_idx, he_u_b, hav_b, m_buf, s_buf, t_buf);
    make_agg<<<ginit, blk, 0, stream>>>(s_buf, t_buf, agg_b);
    gemm_node<true, false><<<gnode, blk, 0, stream>>>(agg_b, W_v_w, W_v_b, NVN, 192, 64, hv_out, 128, 64);
}